// Round 3
// baseline (261701.660 us; speedup 1.0000x reference)
//
#include <hip/hip_runtime.h>
#include <hip/hip_fp16.h>

#define TLEN 16384
#define HD 128
#define NG 384

// ---------------------------------------------------------------------------
// Sequential GRU scan: 4 independent chains (one per channel — the
// reference's stack().transpose(0,2,1) makes "batch" = channel and
// "feature" = original batch row). 1 block per chain, 768 threads.
// Thread t: k = t>>1 (gate-row 0..383), half = t&1 (j-range half*64..+63).
// Weights in VGPRs (launch_bounds(768,3) => 170-reg cap, no spill);
// h in LDS; 2 barriers per step; hs staged via 8-step LDS ring.
// ---------------------------------------------------------------------------
__global__ __launch_bounds__(768, 3) void gru_kernel(
    const float* __restrict__ px,
    const float* __restrict__ py,
    const float* __restrict__ vx,
    const float* __restrict__ vy,
    const float* __restrict__ Wemb,   // [128,4]
    const float* __restrict__ bemb,   // [128]
    const float* __restrict__ Wih,    // [384,128]
    const float* __restrict__ Whh,    // [384,128]
    const float* __restrict__ bih,    // [384]
    const float* __restrict__ bhh,    // [384]
    const int*   __restrict__ step_mask, // [16384]
    const int*   __restrict__ ctxp,      // [1]
    __half*      __restrict__ hs)        // [4*16384*128] f16 staging
{
    const int bb  = blockIdx.x;   // chain == channel
    const float* xsrc = (bb == 0) ? px : (bb == 1) ? py : (bb == 2) ? vx : vy;
    const int tid  = threadIdx.x;
    const int k    = tid >> 1;
    const int half = tid & 1;
    const int jb   = half << 6;   // 0 or 64
    const int cswz = half << 2;   // XOR on c: half=1 reads c^4 -> disjoint banks

    __shared__ float hbuf[HD];
    __shared__ float gigh[2 * NG];     // interleaved (gi, gh) per gate-row k
    __shared__ float hring[8][HD];     // 8-step h history for batched global store
    __shared__ float xbuf[256 * 4];    // prefetched x features
    __shared__ int   uxbuf[256];       // prefetched use_x flags
    __shared__ float WembL[HD * 4];
    __shared__ float bembL[HD];

    // ---- one-time: this thread's weight half-rows into registers
    float wh[64], wi[64];
    {
        const float4* p = (const float4*)(Whh + k * HD + jb);
        const float4* q = (const float4*)(Wih + k * HD + jb);
        #pragma unroll
        for (int c = 0; c < 16; ++c) {
            float4 a = p[c];
            wh[c*4+0] = a.x; wh[c*4+1] = a.y; wh[c*4+2] = a.z; wh[c*4+3] = a.w;
            float4 b = q[c];
            wi[c*4+0] = b.x; wi[c*4+1] = b.y; wi[c*4+2] = b.z; wi[c*4+3] = b.w;
        }
    }
    if (tid < 512)                WembL[tid]       = Wemb[tid];
    if (tid >= 512 && tid < 640)  bembL[tid - 512] = bemb[tid - 512];
    if (tid < HD)                 hbuf[tid]        = 0.f;
    __syncthreads();

    // ---- fold embed into x-path: Wc[k][f] = sum_j Wih[k][j]*Wemb[j][f]
    const float bihv = bih[k];
    const float bhhv = bhh[k];
    float wc0 = 0.f, wc1 = 0.f, wc2 = 0.f, wc3 = 0.f, bcp = 0.f;
    #pragma unroll
    for (int j = 0; j < 64; ++j) {
        const float w = wi[j];
        const float4 e = *(const float4*)&WembL[(jb + j) * 4];
        wc0 = fmaf(w, e.x, wc0); wc1 = fmaf(w, e.y, wc1);
        wc2 = fmaf(w, e.z, wc2); wc3 = fmaf(w, e.w, wc3);
        bcp = fmaf(w, bembL[jb + j], bcp);
    }
    wc0 += __shfl_xor(wc0, 1, 64); wc1 += __shfl_xor(wc1, 1, 64);
    wc2 += __shfl_xor(wc2, 1, 64); wc3 += __shfl_xor(wc3, 1, 64);
    bcp += __shfl_xor(bcp, 1, 64);
    const float bc   = bihv + bcp;
    const int   ctxm = (ctxp[0] < 1) ? 1 : ctxp[0];

    for (int t0 = 0; t0 < TLEN; t0 += 256) {
        // prefetch x + use_x (prev step's trailing barrier protects xbuf)
        if (tid < 256) {
            const int gt = t0 + tid;
            xbuf[tid*4+0] = xsrc[0*TLEN + gt];
            xbuf[tid*4+1] = xsrc[1*TLEN + gt];
            xbuf[tid*4+2] = xsrc[2*TLEN + gt];
            xbuf[tid*4+3] = xsrc[3*TLEN + gt];
            uxbuf[tid] = ((gt < ctxm) || (step_mask[gt] == 0)) ? 1 : 0;
        }
        __syncthreads();
        for (int tt = 0; tt < 256; ++tt) {
            const int ux = __builtin_amdgcn_readfirstlane(uxbuf[tt]);
            float agh = 0.f, agi = 0.f;
            if (ux) {
                #pragma unroll
                for (int c = 0; c < 16; ++c) {
                    const int cx = c ^ cswz;   // bank-conflict-free pairing
                    const float4 h4 = *(const float4*)&hbuf[jb + cx*4];
                    agh = fmaf(wh[cx*4+0], h4.x, agh);
                    agh = fmaf(wh[cx*4+1], h4.y, agh);
                    agh = fmaf(wh[cx*4+2], h4.z, agh);
                    agh = fmaf(wh[cx*4+3], h4.w, agh);
                }
            } else {
                #pragma unroll
                for (int c = 0; c < 16; ++c) {
                    const int cx = c ^ cswz;
                    const float4 h4 = *(const float4*)&hbuf[jb + cx*4];
                    agh = fmaf(wh[cx*4+0], h4.x, agh); agi = fmaf(wi[cx*4+0], h4.x, agi);
                    agh = fmaf(wh[cx*4+1], h4.y, agh); agi = fmaf(wi[cx*4+1], h4.y, agi);
                    agh = fmaf(wh[cx*4+2], h4.z, agh); agi = fmaf(wi[cx*4+2], h4.z, agi);
                    agh = fmaf(wh[cx*4+3], h4.w, agh); agi = fmaf(wi[cx*4+3], h4.w, agi);
                }
            }
            agh += __shfl_xor(agh, 1, 64);
            agi += __shfl_xor(agi, 1, 64);
            if (half == 0) {
                const float gh = agh + bhhv;
                float gi;
                if (ux) {
                    const float4 xv = *(const float4*)&xbuf[tt*4];
                    gi = bc;
                    gi = fmaf(wc0, xv.x, gi); gi = fmaf(wc1, xv.y, gi);
                    gi = fmaf(wc2, xv.z, gi); gi = fmaf(wc3, xv.w, gi);
                } else {
                    gi = agi + bihv;
                }
                *(float2*)&gigh[2*k] = make_float2(gi, gh);
            }
            __syncthreads();
            // gates + state update (PyTorch GRUCell: r,z,n order)
            if (tid < HD) {
                const float2 gr = *(const float2*)&gigh[2*tid];
                const float2 gz = *(const float2*)&gigh[2*(HD + tid)];
                const float2 gn = *(const float2*)&gigh[2*(2*HD + tid)];
                const float r    = 1.f / (1.f + __expf(-(gr.x + gr.y)));
                const float z    = 1.f / (1.f + __expf(-(gz.x + gz.y)));
                const float npre = fmaf(r, gn.y, gn.x);
                const float e2   = __expf(2.f * npre);
                const float n    = 1.f - 2.f / (e2 + 1.f);       // tanh(npre)
                const float hold = hbuf[tid];
                const float hnew = fmaf(z, hold - n, n);         // (1-z)*n + z*h
                hbuf[tid] = hnew;
                hring[tt & 7][tid] = hnew;
            }
            __syncthreads();
            // flush h history to global every 8 steps from waves 2-3 (tid
            // 128..255): their store drain overlaps the next compute phase
            // instead of stalling the per-step barrier.
            if ((tt & 7) == 7 && tid >= 128 && tid < 256) {
                const int q = tid - 128;
                const int base = bb * TLEN + t0 + tt - 7;
                #pragma unroll
                for (int j = 0; j < 8; ++j) {
                    hs[(size_t)(base + j) * HD + q] = __float2half(hring[j][q]);
                }
            }
        }
    }
}

// ---------------------------------------------------------------------------
// Head MLP over all 65536 hidden states: thread-per-row, weights uniform in
// LDS (broadcast reads), h in registers, y1 in padded LDS (stride 65).
// ---------------------------------------------------------------------------
__global__ __launch_bounds__(64) void head_kernel(
    const float*  __restrict__ W1,  // [64,128]
    const float*  __restrict__ b1,  // [64]
    const float*  __restrict__ W2,  // [64,64]
    const float*  __restrict__ b2,  // [64]
    const float*  __restrict__ W3,  // [2,64]
    const float*  __restrict__ b3,  // [2]
    const __half* __restrict__ hs,
    float*        __restrict__ out)
{
    __shared__ float W1L[64 * 128];
    __shared__ float W2L[64 * 64];
    __shared__ float W3L[2 * 64];
    __shared__ float b1L[64], b2L[64], b3L[2];
    __shared__ float y1L[64 * 65];   // per-thread row, stride 65 (bank pad)

    const int tid = threadIdx.x;
    {
        float4* dst1 = (float4*)W1L; const float4* src1 = (const float4*)W1;
        for (int i = tid; i < 2048; i += 64) dst1[i] = src1[i];
        float4* dst2 = (float4*)W2L; const float4* src2 = (const float4*)W2;
        for (int i = tid; i < 1024; i += 64) dst2[i] = src2[i];
        if (tid < 32) ((float4*)W3L)[tid] = ((const float4*)W3)[tid];
        b1L[tid] = b1[tid];
        b2L[tid] = b2[tid];
        if (tid < 2) b3L[tid] = b3[tid];
    }
    __syncthreads();

    const int row = blockIdx.x * 64 + tid;   // row = bb*16384 + t
    float h[128];
    {
        const uint4* hp = (const uint4*)(hs + (size_t)row * HD);
        #pragma unroll
        for (int c = 0; c < 16; ++c) {
            uint4 q = hp[c];
            const __half2* hh = (const __half2*)&q;
            #pragma unroll
            for (int d = 0; d < 4; ++d) {
                const float2 f = __half22float2(hh[d]);
                h[c*8 + d*2 + 0] = f.x;
                h[c*8 + d*2 + 1] = f.y;
            }
        }
    }
    // layer 1: y1 = elu(W1 h + b1)
    for (int l = 0; l < 64; ++l) {
        float a0 = b1L[l], a1 = 0.f;
        #pragma unroll
        for (int j = 0; j < 128; j += 4) {
            const float4 w = *(const float4*)&W1L[l*128 + j];
            a0 = fmaf(w.x, h[j+0], a0);
            a1 = fmaf(w.y, h[j+1], a1);
            a0 = fmaf(w.z, h[j+2], a0);
            a1 = fmaf(w.w, h[j+3], a1);
        }
        const float acc = a0 + a1;
        y1L[tid * 65 + l] = (acc > 0.f) ? acc : (__expf(acc) - 1.f);
    }
    // layer 2 + layer 3 fused: y3 += W3 * elu(W2 y1 + b2)
    float y30 = b3L[0], y31 = b3L[1];
    for (int l = 0; l < 64; ++l) {
        float a0 = b2L[l], a1 = 0.f;
        const int yb = tid * 65;
        #pragma unroll
        for (int j = 0; j < 64; j += 4) {
            const float4 w = *(const float4*)&W2L[l*64 + j];
            a0 = fmaf(w.x, y1L[yb + j+0], a0);
            a1 = fmaf(w.y, y1L[yb + j+1], a1);
            a0 = fmaf(w.z, y1L[yb + j+2], a0);
            a1 = fmaf(w.w, y1L[yb + j+3], a1);
        }
        const float acc = a0 + a1;
        const float v = (acc > 0.f) ? acc : (__expf(acc) - 1.f);
        y30 = fmaf(W3L[l],      v, y30);
        y31 = fmaf(W3L[64 + l], v, y31);
    }
    out[row]            = y30;
    out[4 * TLEN + row] = y31;
}

extern "C" void kernel_launch(void* const* d_in, const int* in_sizes, int n_in,
                              void* d_out, int out_size, void* d_ws, size_t ws_size,
                              hipStream_t stream) {
    const float* px   = (const float*)d_in[0];
    const float* py   = (const float*)d_in[1];
    const float* vx   = (const float*)d_in[2];
    const float* vy   = (const float*)d_in[3];
    const float* Wemb = (const float*)d_in[4];
    const float* bemb = (const float*)d_in[5];
    const float* Wih  = (const float*)d_in[6];
    const float* Whh  = (const float*)d_in[7];
    const float* bih  = (const float*)d_in[8];
    const float* bhh  = (const float*)d_in[9];
    const float* W1   = (const float*)d_in[10];
    const float* b1   = (const float*)d_in[11];
    const float* W2   = (const float*)d_in[12];
    const float* b2   = (const float*)d_in[13];
    const float* W3   = (const float*)d_in[14];
    const float* b3   = (const float*)d_in[15];
    const int* step_mask = (const int*)d_in[16];
    const int* ctx       = (const int*)d_in[17];
    __half* hs = (__half*)d_ws;          // 4*16384*128 f16 = 16.8 MB
    float* out = (float*)d_out;          // f32, [2][4][16384] flat

    hipLaunchKernelGGL(gru_kernel, dim3(4), dim3(768), 0, stream,
                       px, py, vx, vy, Wemb, bemb, Wih, Whh, bih, bhh,
                       step_mask, ctx, hs);
    hipLaunchKernelGGL(head_kernel, dim3(1024), dim3(64), 0, stream,
                       W1, b1, W2, b2, W3, b3, hs, out);
}

// Round 4
// 58706.708 us; speedup vs baseline: 4.4578x; 4.4578x over previous
//
#include <hip/hip_runtime.h>
#include <hip/hip_fp16.h>

#define TLEN 16384
#define HD 128
#define NG 384

// ---------------------------------------------------------------------------
// Sequential GRU scan: 4 independent chains (one per channel — the
// reference's stack().transpose(0,2,1) makes "batch" = channel and
// "feature" = original batch row). 1 block per chain, 768 threads.
// Thread t: k = t>>1 (gate-row 0..383), half = t&1.
// half owns the even/odd float4-chunks of the row: columns (2c+half)*4..+3,
// c = 0..15.  =>  at unroll position c, even lanes read LDS words 8c..8c+3,
// odd lanes 8c+4..8c+7: disjoint banks (conflict-free), compile-time ds
// offsets, compile-time register indices (NO scratch spill — the R3 lesson).
// Weights in VGPRs (launch_bounds(768,3) => 170-reg cap); h in LDS;
// 2 barriers/step; hs staged via 8-step LDS ring flushed by waves 2-3.
// ---------------------------------------------------------------------------
__global__ __launch_bounds__(768, 3) void gru_kernel(
    const float* __restrict__ px,
    const float* __restrict__ py,
    const float* __restrict__ vx,
    const float* __restrict__ vy,
    const float* __restrict__ Wemb,   // [128,4]
    const float* __restrict__ bemb,   // [128]
    const float* __restrict__ Wih,    // [384,128]
    const float* __restrict__ Whh,    // [384,128]
    const float* __restrict__ bih,    // [384]
    const float* __restrict__ bhh,    // [384]
    const int*   __restrict__ step_mask, // [16384]
    const int*   __restrict__ ctxp,      // [1]
    __half*      __restrict__ hs)        // [4*16384*128] f16 staging
{
    const int bb  = blockIdx.x;   // chain == channel
    const float* xsrc = (bb == 0) ? px : (bb == 1) ? py : (bb == 2) ? vx : vy;
    const int tid  = threadIdx.x;
    const int k    = tid >> 1;
    const int half = tid & 1;

    __shared__ float hbuf[HD];
    __shared__ float gigh[2 * NG];     // interleaved (gi, gh) per gate-row k
    __shared__ float hring[8][HD];     // 8-step h history for batched store
    __shared__ float xbuf[256 * 4];    // prefetched x features
    __shared__ int   uxbuf[256];       // prefetched use_x flags
    __shared__ float WembL[HD * 4];
    __shared__ float bembL[HD];

    // ---- one-time: this thread's weight chunks into registers.
    // Register slot c holds the float4 for columns (2c+half)*4..+3.
    float wh[64], wi[64];
    {
        const float4* p = (const float4*)(Whh + k * HD) + half;
        const float4* q = (const float4*)(Wih + k * HD) + half;
        #pragma unroll
        for (int c = 0; c < 16; ++c) {
            float4 a = p[2*c];
            wh[c*4+0] = a.x; wh[c*4+1] = a.y; wh[c*4+2] = a.z; wh[c*4+3] = a.w;
            float4 b = q[2*c];
            wi[c*4+0] = b.x; wi[c*4+1] = b.y; wi[c*4+2] = b.z; wi[c*4+3] = b.w;
        }
    }
    if (tid < 512)                WembL[tid]       = Wemb[tid];
    if (tid >= 512 && tid < 640)  bembL[tid - 512] = bemb[tid - 512];
    if (tid < HD)                 hbuf[tid]        = 0.f;
    __syncthreads();

    // ---- fold embed into x-path: Wc[k][f] = sum_j Wih[k][j]*Wemb[j][f]
    // (this thread's j-set = its owned columns; shuffle-pair completes the sum)
    const float bihv = bih[k];
    const float bhhv = bhh[k];
    float wc0 = 0.f, wc1 = 0.f, wc2 = 0.f, wc3 = 0.f, bcp = 0.f;
    #pragma unroll
    for (int c = 0; c < 16; ++c) {
        #pragma unroll
        for (int r = 0; r < 4; ++r) {
            const int col = ((2*c + half) << 2) + r;   // one-time, runtime ok
            const float w = wi[c*4 + r];
            const float4 e = *(const float4*)&WembL[col * 4];
            wc0 = fmaf(w, e.x, wc0); wc1 = fmaf(w, e.y, wc1);
            wc2 = fmaf(w, e.z, wc2); wc3 = fmaf(w, e.w, wc3);
            bcp = fmaf(w, bembL[col], bcp);
        }
    }
    wc0 += __shfl_xor(wc0, 1, 64); wc1 += __shfl_xor(wc1, 1, 64);
    wc2 += __shfl_xor(wc2, 1, 64); wc3 += __shfl_xor(wc3, 1, 64);
    bcp += __shfl_xor(bcp, 1, 64);
    const float bc   = bihv + bcp;
    const int   ctxm = (ctxp[0] < 1) ? 1 : ctxp[0];

    // per-thread LDS base for the h reads: chunk (2c+half) => 4*half + 8c floats
    const float* hb = hbuf + (half << 2);

    for (int t0 = 0; t0 < TLEN; t0 += 256) {
        // prefetch x + use_x (prev step's trailing barrier protects xbuf)
        if (tid < 256) {
            const int gt = t0 + tid;
            xbuf[tid*4+0] = xsrc[0*TLEN + gt];
            xbuf[tid*4+1] = xsrc[1*TLEN + gt];
            xbuf[tid*4+2] = xsrc[2*TLEN + gt];
            xbuf[tid*4+3] = xsrc[3*TLEN + gt];
            uxbuf[tid] = ((gt < ctxm) || (step_mask[gt] == 0)) ? 1 : 0;
        }
        __syncthreads();
        for (int tt = 0; tt < 256; ++tt) {
            const int ux = __builtin_amdgcn_readfirstlane(uxbuf[tt]);
            float agh = 0.f, agi = 0.f;
            if (ux) {
                #pragma unroll
                for (int c = 0; c < 16; ++c) {
                    const float4 h4 = *(const float4*)&hb[c << 3];  // imm offset
                    agh = fmaf(wh[c*4+0], h4.x, agh);
                    agh = fmaf(wh[c*4+1], h4.y, agh);
                    agh = fmaf(wh[c*4+2], h4.z, agh);
                    agh = fmaf(wh[c*4+3], h4.w, agh);
                }
            } else {
                #pragma unroll
                for (int c = 0; c < 16; ++c) {
                    const float4 h4 = *(const float4*)&hb[c << 3];
                    agh = fmaf(wh[c*4+0], h4.x, agh); agi = fmaf(wi[c*4+0], h4.x, agi);
                    agh = fmaf(wh[c*4+1], h4.y, agh); agi = fmaf(wi[c*4+1], h4.y, agi);
                    agh = fmaf(wh[c*4+2], h4.z, agh); agi = fmaf(wi[c*4+2], h4.z, agi);
                    agh = fmaf(wh[c*4+3], h4.w, agh); agi = fmaf(wi[c*4+3], h4.w, agi);
                }
            }
            agh += __shfl_xor(agh, 1, 64);
            agi += __shfl_xor(agi, 1, 64);
            if (half == 0) {
                const float gh = agh + bhhv;
                float gi;
                if (ux) {
                    const float4 xv = *(const float4*)&xbuf[tt*4];
                    gi = bc;
                    gi = fmaf(wc0, xv.x, gi); gi = fmaf(wc1, xv.y, gi);
                    gi = fmaf(wc2, xv.z, gi); gi = fmaf(wc3, xv.w, gi);
                } else {
                    gi = agi + bihv;
                }
                *(float2*)&gigh[2*k] = make_float2(gi, gh);
            }
            __syncthreads();
            // gates + state update (PyTorch GRUCell: r,z,n order)
            if (tid < HD) {
                const float2 gr = *(const float2*)&gigh[2*tid];
                const float2 gz = *(const float2*)&gigh[2*(HD + tid)];
                const float2 gn = *(const float2*)&gigh[2*(2*HD + tid)];
                const float r    = 1.f / (1.f + __expf(-(gr.x + gr.y)));
                const float z    = 1.f / (1.f + __expf(-(gz.x + gz.y)));
                const float npre = fmaf(r, gn.y, gn.x);
                const float e2   = __expf(2.f * npre);
                const float n    = 1.f - 2.f / (e2 + 1.f);       // tanh(npre)
                const float hold = hbuf[tid];
                const float hnew = fmaf(z, hold - n, n);         // (1-z)*n + z*h
                hbuf[tid] = hnew;
                hring[tt & 7][tid] = hnew;
            }
            __syncthreads();
            // flush h history every 8 steps from waves 2-3: their store
            // drain overlaps the next compute phase instead of stalling
            // the per-step barrier.
            if ((tt & 7) == 7 && tid >= 128 && tid < 256) {
                const int q = tid - 128;
                const int base = bb * TLEN + t0 + tt - 7;
                #pragma unroll
                for (int j = 0; j < 8; ++j) {
                    hs[(size_t)(base + j) * HD + q] = __float2half(hring[j][q]);
                }
            }
        }
    }
}

// ---------------------------------------------------------------------------
// Head MLP over all 65536 hidden states: thread-per-row, weights uniform in
// LDS (broadcast reads), h in registers, y1 in padded LDS (stride 65).
// ---------------------------------------------------------------------------
__global__ __launch_bounds__(64) void head_kernel(
    const float*  __restrict__ W1,  // [64,128]
    const float*  __restrict__ b1,  // [64]
    const float*  __restrict__ W2,  // [64,64]
    const float*  __restrict__ b2,  // [64]
    const float*  __restrict__ W3,  // [2,64]
    const float*  __restrict__ b3,  // [2]
    const __half* __restrict__ hs,
    float*        __restrict__ out)
{
    __shared__ float W1L[64 * 128];
    __shared__ float W2L[64 * 64];
    __shared__ float W3L[2 * 64];
    __shared__ float b1L[64], b2L[64], b3L[2];
    __shared__ float y1L[64 * 65];   // per-thread row, stride 65 (bank pad)

    const int tid = threadIdx.x;
    {
        float4* dst1 = (float4*)W1L; const float4* src1 = (const float4*)W1;
        for (int i = tid; i < 2048; i += 64) dst1[i] = src1[i];
        float4* dst2 = (float4*)W2L; const float4* src2 = (const float4*)W2;
        for (int i = tid; i < 1024; i += 64) dst2[i] = src2[i];
        if (tid < 32) ((float4*)W3L)[tid] = ((const float4*)W3)[tid];
        b1L[tid] = b1[tid];
        b2L[tid] = b2[tid];
        if (tid < 2) b3L[tid] = b3[tid];
    }
    __syncthreads();

    const int row = blockIdx.x * 64 + tid;   // row = bb*16384 + t
    float h[128];
    {
        const uint4* hp = (const uint4*)(hs + (size_t)row * HD);
        #pragma unroll
        for (int c = 0; c < 16; ++c) {
            uint4 q = hp[c];
            const __half2* hh = (const __half2*)&q;
            #pragma unroll
            for (int d = 0; d < 4; ++d) {
                const float2 f = __half22float2(hh[d]);
                h[c*8 + d*2 + 0] = f.x;
                h[c*8 + d*2 + 1] = f.y;
            }
        }
    }
    // layer 1: y1 = elu(W1 h + b1)
    for (int l = 0; l < 64; ++l) {
        float a0 = b1L[l], a1 = 0.f;
        #pragma unroll
        for (int j = 0; j < 128; j += 4) {
            const float4 w = *(const float4*)&W1L[l*128 + j];
            a0 = fmaf(w.x, h[j+0], a0);
            a1 = fmaf(w.y, h[j+1], a1);
            a0 = fmaf(w.z, h[j+2], a0);
            a1 = fmaf(w.w, h[j+3], a1);
        }
        const float acc = a0 + a1;
        y1L[tid * 65 + l] = (acc > 0.f) ? acc : (__expf(acc) - 1.f);
    }
    // layer 2 + layer 3 fused: y3 += W3 * elu(W2 y1 + b2)
    float y30 = b3L[0], y31 = b3L[1];
    for (int l = 0; l < 64; ++l) {
        float a0 = b2L[l], a1 = 0.f;
        const int yb = tid * 65;
        #pragma unroll
        for (int j = 0; j < 64; j += 4) {
            const float4 w = *(const float4*)&W2L[l*64 + j];
            a0 = fmaf(w.x, y1L[yb + j+0], a0);
            a1 = fmaf(w.y, y1L[yb + j+1], a1);
            a0 = fmaf(w.z, y1L[yb + j+2], a0);
            a1 = fmaf(w.w, y1L[yb + j+3], a1);
        }
        const float acc = a0 + a1;
        const float v = (acc > 0.f) ? acc : (__expf(acc) - 1.f);
        y30 = fmaf(W3L[l],      v, y30);
        y31 = fmaf(W3L[64 + l], v, y31);
    }
    out[row]            = y30;
    out[4 * TLEN + row] = y31;
}

extern "C" void kernel_launch(void* const* d_in, const int* in_sizes, int n_in,
                              void* d_out, int out_size, void* d_ws, size_t ws_size,
                              hipStream_t stream) {
    const float* px   = (const float*)d_in[0];
    const float* py   = (const float*)d_in[1];
    const float* vx   = (const float*)d_in[2];
    const float* vy   = (const float*)d_in[3];
    const float* Wemb = (const float*)d_in[4];
    const float* bemb = (const float*)d_in[5];
    const float* Wih  = (const float*)d_in[6];
    const float* Whh  = (const float*)d_in[7];
    const float* bih  = (const float*)d_in[8];
    const float* bhh  = (const float*)d_in[9];
    const float* W1   = (const float*)d_in[10];
    const float* b1   = (const float*)d_in[11];
    const float* W2   = (const float*)d_in[12];
    const float* b2   = (const float*)d_in[13];
    const float* W3   = (const float*)d_in[14];
    const float* b3   = (const float*)d_in[15];
    const int* step_mask = (const int*)d_in[16];
    const int* ctx       = (const int*)d_in[17];
    __half* hs = (__half*)d_ws;          // 4*16384*128 f16 = 16.8 MB
    float* out = (float*)d_out;          // f32, [2][4][16384] flat

    hipLaunchKernelGGL(gru_kernel, dim3(4), dim3(768), 0, stream,
                       px, py, vx, vy, Wemb, bemb, Wih, Whh, bih, bhh,
                       step_mask, ctx, hs);
    hipLaunchKernelGGL(head_kernel, dim3(1024), dim3(64), 0, stream,
                       W1, b1, W2, b2, W3, b3, hs, out);
}

// Round 5
// 55499.255 us; speedup vs baseline: 4.7154x; 1.0578x over previous
//
#include <hip/hip_runtime.h>
#include <hip/hip_fp16.h>

#define TLEN 16384
#define HD 128
#define NG 384

// ---------------------------------------------------------------------------
// Sequential GRU scan: 4 independent chains (one per channel — the
// reference's stack().transpose(0,2,1) makes "batch" = channel and
// "feature" = original batch row). 1 block per chain, 768 threads.
// Thread t: k = t>>1 (gate-row 0..383), half = t&1.
// half owns the even/odd float4-chunks of the row: columns (2c+half)*4..+3.
// At unroll position c, even lanes read LDS words 8c..8c+3, odd lanes
// 8c+4..8c+7: disjoint banks (conflict-free, verified R4: conflicts=0).
// R5 FIX: weights live in 32 NAMED float4 variables (macro-expanded), not
// C arrays — SROA demoted the arrays to scratch before unrolling (R2/R4
// VGPR_Count=84), making the kernel L2-bound on weight reloads.
// ---------------------------------------------------------------------------

#define FOR16(X) X(0) X(1) X(2) X(3) X(4) X(5) X(6) X(7) \
                 X(8) X(9) X(10) X(11) X(12) X(13) X(14) X(15)

__global__ __launch_bounds__(768, 3) void gru_kernel(
    const float* __restrict__ px,
    const float* __restrict__ py,
    const float* __restrict__ vx,
    const float* __restrict__ vy,
    const float* __restrict__ Wemb,   // [128,4]
    const float* __restrict__ bemb,   // [128]
    const float* __restrict__ Wih,    // [384,128]
    const float* __restrict__ Whh,    // [384,128]
    const float* __restrict__ bih,    // [384]
    const float* __restrict__ bhh,    // [384]
    const int*   __restrict__ step_mask, // [16384]
    const int*   __restrict__ ctxp,      // [1]
    __half*      __restrict__ hs)        // [4*16384*128] f16 staging
{
    const int bb  = blockIdx.x;   // chain == channel
    const float* xsrc = (bb == 0) ? px : (bb == 1) ? py : (bb == 2) ? vx : vy;
    const int tid  = threadIdx.x;
    const int k    = tid >> 1;
    const int half = tid & 1;

    __shared__ float hbuf[HD];
    __shared__ float gigh[2 * NG];     // interleaved (gi, gh) per gate-row k
    __shared__ float hring[8][HD];     // 8-step h history for batched store
    __shared__ float xbuf[256 * 4];    // prefetched x features
    __shared__ int   uxbuf[256];       // prefetched use_x flags
    __shared__ float WembL[HD * 4];
    __shared__ float bembL[HD];

    // ---- weights in NAMED float4 registers (cannot be scratch-demoted)
#define DECLW(c) float4 wh##c, wi##c;
    FOR16(DECLW)
#undef DECLW
    {
        const float4* p = (const float4*)(Whh + k * HD) + half;
        const float4* q = (const float4*)(Wih + k * HD) + half;
#define LOADW(c) wh##c = p[2*(c)]; wi##c = q[2*(c)];
        FOR16(LOADW)
#undef LOADW
    }
    if (tid < 512)                WembL[tid]       = Wemb[tid];
    if (tid >= 512 && tid < 640)  bembL[tid - 512] = bemb[tid - 512];
    if (tid < HD)                 hbuf[tid]        = 0.f;
    __syncthreads();

    // ---- fold embed into x-path: Wc[k][f] = sum_j Wih[k][j]*Wemb[j][f]
    const float bihv = bih[k];
    const float bhhv = bhh[k];
    float wc0 = 0.f, wc1 = 0.f, wc2 = 0.f, wc3 = 0.f, bcp = 0.f;
#define EF1(c, comp, r) { \
        const float w = wi##c.comp; \
        const int col = ((2*(c) + half) << 2) + (r); \
        const float4 e = *(const float4*)&WembL[col * 4]; \
        wc0 = fmaf(w, e.x, wc0); wc1 = fmaf(w, e.y, wc1); \
        wc2 = fmaf(w, e.z, wc2); wc3 = fmaf(w, e.w, wc3); \
        bcp = fmaf(w, bembL[col], bcp); }
#define EFOLD(c) EF1(c, x, 0) EF1(c, y, 1) EF1(c, z, 2) EF1(c, w, 3)
    FOR16(EFOLD)
#undef EFOLD
#undef EF1
    wc0 += __shfl_xor(wc0, 1, 64); wc1 += __shfl_xor(wc1, 1, 64);
    wc2 += __shfl_xor(wc2, 1, 64); wc3 += __shfl_xor(wc3, 1, 64);
    bcp += __shfl_xor(bcp, 1, 64);
    const float bc   = bihv + bcp;
    const int   ctxm = (ctxp[0] < 1) ? 1 : ctxp[0];

    // per-thread LDS base for h reads: chunk (2c+half) => floats 4*half + 8c
    const float* hb = hbuf + (half << 2);

    for (int t0 = 0; t0 < TLEN; t0 += 256) {
        // prefetch x + use_x (prev step's trailing barrier protects xbuf)
        if (tid < 256) {
            const int gt = t0 + tid;
            xbuf[tid*4+0] = xsrc[0*TLEN + gt];
            xbuf[tid*4+1] = xsrc[1*TLEN + gt];
            xbuf[tid*4+2] = xsrc[2*TLEN + gt];
            xbuf[tid*4+3] = xsrc[3*TLEN + gt];
            uxbuf[tid] = ((gt < ctxm) || (step_mask[gt] == 0)) ? 1 : 0;
        }
        __syncthreads();
        for (int tt = 0; tt < 256; ++tt) {
            const int ux = __builtin_amdgcn_readfirstlane(uxbuf[tt]);
            float agh = 0.f, agi = 0.f;
            if (ux) {
#define STEPH(c) { \
                const float4 h4 = *(const float4*)&hb[(c) << 3]; \
                agh = fmaf(wh##c.x, h4.x, agh); \
                agh = fmaf(wh##c.y, h4.y, agh); \
                agh = fmaf(wh##c.z, h4.z, agh); \
                agh = fmaf(wh##c.w, h4.w, agh); }
                FOR16(STEPH)
#undef STEPH
            } else {
#define STEPHI(c) { \
                const float4 h4 = *(const float4*)&hb[(c) << 3]; \
                agh = fmaf(wh##c.x, h4.x, agh); agi = fmaf(wi##c.x, h4.x, agi); \
                agh = fmaf(wh##c.y, h4.y, agh); agi = fmaf(wi##c.y, h4.y, agi); \
                agh = fmaf(wh##c.z, h4.z, agh); agi = fmaf(wi##c.z, h4.z, agi); \
                agh = fmaf(wh##c.w, h4.w, agh); agi = fmaf(wi##c.w, h4.w, agi); }
                FOR16(STEPHI)
#undef STEPHI
            }
            agh += __shfl_xor(agh, 1, 64);
            agi += __shfl_xor(agi, 1, 64);
            if (half == 0) {
                const float gh = agh + bhhv;
                float gi;
                if (ux) {
                    const float4 xv = *(const float4*)&xbuf[tt*4];
                    gi = bc;
                    gi = fmaf(wc0, xv.x, gi); gi = fmaf(wc1, xv.y, gi);
                    gi = fmaf(wc2, xv.z, gi); gi = fmaf(wc3, xv.w, gi);
                } else {
                    gi = agi + bihv;
                }
                *(float2*)&gigh[2*k] = make_float2(gi, gh);
            }
            __syncthreads();
            // gates + state update (PyTorch GRUCell: r,z,n order)
            if (tid < HD) {
                const float2 gr = *(const float2*)&gigh[2*tid];
                const float2 gz = *(const float2*)&gigh[2*(HD + tid)];
                const float2 gn = *(const float2*)&gigh[2*(2*HD + tid)];
                const float r    = 1.f / (1.f + __expf(-(gr.x + gr.y)));
                const float z    = 1.f / (1.f + __expf(-(gz.x + gz.y)));
                const float npre = fmaf(r, gn.y, gn.x);
                const float e2   = __expf(2.f * npre);
                const float n    = 1.f - 2.f / (e2 + 1.f);       // tanh(npre)
                const float hold = hbuf[tid];
                const float hnew = fmaf(z, hold - n, n);         // (1-z)*n + z*h
                hbuf[tid] = hnew;
                hring[tt & 7][tid] = hnew;
            }
            __syncthreads();
            // flush h history every 8 steps from waves 2-3: store drain
            // overlaps the next compute phase instead of the step barrier.
            if ((tt & 7) == 7 && tid >= 128 && tid < 256) {
                const int q = tid - 128;
                const int base = bb * TLEN + t0 + tt - 7;
                #pragma unroll
                for (int j = 0; j < 8; ++j) {
                    hs[(size_t)(base + j) * HD + q] = __float2half(hring[j][q]);
                }
            }
        }
    }
}

// ---------------------------------------------------------------------------
// Head MLP over all 65536 hidden states: thread-per-row, weights uniform in
// LDS (broadcast reads), h in registers, y1 in padded LDS (stride 65).
// ---------------------------------------------------------------------------
__global__ __launch_bounds__(64) void head_kernel(
    const float*  __restrict__ W1,  // [64,128]
    const float*  __restrict__ b1,  // [64]
    const float*  __restrict__ W2,  // [64,64]
    const float*  __restrict__ b2,  // [64]
    const float*  __restrict__ W3,  // [2,64]
    const float*  __restrict__ b3,  // [2]
    const __half* __restrict__ hs,
    float*        __restrict__ out)
{
    __shared__ float W1L[64 * 128];
    __shared__ float W2L[64 * 64];
    __shared__ float W3L[2 * 64];
    __shared__ float b1L[64], b2L[64], b3L[2];
    __shared__ float y1L[64 * 65];   // per-thread row, stride 65 (bank pad)

    const int tid = threadIdx.x;
    {
        float4* dst1 = (float4*)W1L; const float4* src1 = (const float4*)W1;
        for (int i = tid; i < 2048; i += 64) dst1[i] = src1[i];
        float4* dst2 = (float4*)W2L; const float4* src2 = (const float4*)W2;
        for (int i = tid; i < 1024; i += 64) dst2[i] = src2[i];
        if (tid < 32) ((float4*)W3L)[tid] = ((const float4*)W3)[tid];
        b1L[tid] = b1[tid];
        b2L[tid] = b2[tid];
        if (tid < 2) b3L[tid] = b3[tid];
    }
    __syncthreads();

    const int row = blockIdx.x * 64 + tid;   // row = bb*16384 + t
    float h[128];
    {
        const uint4* hp = (const uint4*)(hs + (size_t)row * HD);
        #pragma unroll
        for (int c = 0; c < 16; ++c) {
            uint4 q = hp[c];
            const __half2* hh = (const __half2*)&q;
            #pragma unroll
            for (int d = 0; d < 4; ++d) {
                const float2 f = __half22float2(hh[d]);
                h[c*8 + d*2 + 0] = f.x;
                h[c*8 + d*2 + 1] = f.y;
            }
        }
    }
    // layer 1: y1 = elu(W1 h + b1)
    for (int l = 0; l < 64; ++l) {
        float a0 = b1L[l], a1 = 0.f;
        #pragma unroll
        for (int j = 0; j < 128; j += 4) {
            const float4 w = *(const float4*)&W1L[l*128 + j];
            a0 = fmaf(w.x, h[j+0], a0);
            a1 = fmaf(w.y, h[j+1], a1);
            a0 = fmaf(w.z, h[j+2], a0);
            a1 = fmaf(w.w, h[j+3], a1);
        }
        const float acc = a0 + a1;
        y1L[tid * 65 + l] = (acc > 0.f) ? acc : (__expf(acc) - 1.f);
    }
    // layer 2 + layer 3 fused: y3 += W3 * elu(W2 y1 + b2)
    float y30 = b3L[0], y31 = b3L[1];
    for (int l = 0; l < 64; ++l) {
        float a0 = b2L[l], a1 = 0.f;
        const int yb = tid * 65;
        #pragma unroll
        for (int j = 0; j < 64; j += 4) {
            const float4 w = *(const float4*)&W2L[l*64 + j];
            a0 = fmaf(w.x, y1L[yb + j+0], a0);
            a1 = fmaf(w.y, y1L[yb + j+1], a1);
            a0 = fmaf(w.z, y1L[yb + j+2], a0);
            a1 = fmaf(w.w, y1L[yb + j+3], a1);
        }
        const float acc = a0 + a1;
        const float v = (acc > 0.f) ? acc : (__expf(acc) - 1.f);
        y30 = fmaf(W3L[l],      v, y30);
        y31 = fmaf(W3L[64 + l], v, y31);
    }
    out[row]            = y30;
    out[4 * TLEN + row] = y31;
}

extern "C" void kernel_launch(void* const* d_in, const int* in_sizes, int n_in,
                              void* d_out, int out_size, void* d_ws, size_t ws_size,
                              hipStream_t stream) {
    const float* px   = (const float*)d_in[0];
    const float* py   = (const float*)d_in[1];
    const float* vx   = (const float*)d_in[2];
    const float* vy   = (const float*)d_in[3];
    const float* Wemb = (const float*)d_in[4];
    const float* bemb = (const float*)d_in[5];
    const float* Wih  = (const float*)d_in[6];
    const float* Whh  = (const float*)d_in[7];
    const float* bih  = (const float*)d_in[8];
    const float* bhh  = (const float*)d_in[9];
    const float* W1   = (const float*)d_in[10];
    const float* b1   = (const float*)d_in[11];
    const float* W2   = (const float*)d_in[12];
    const float* b2   = (const float*)d_in[13];
    const float* W3   = (const float*)d_in[14];
    const float* b3   = (const float*)d_in[15];
    const int* step_mask = (const int*)d_in[16];
    const int* ctx       = (const int*)d_in[17];
    __half* hs = (__half*)d_ws;          // 4*16384*128 f16 = 16.8 MB
    float* out = (float*)d_out;          // f32, [2][4][16384] flat

    hipLaunchKernelGGL(gru_kernel, dim3(4), dim3(768), 0, stream,
                       px, py, vx, vy, Wemb, bemb, Wih, Whh, bih, bhh,
                       step_mask, ctx, hs);
    hipLaunchKernelGGL(head_kernel, dim3(1024), dim3(64), 0, stream,
                       W1, b1, W2, b2, W3, b3, hs, out);
}

// Round 6
// 21161.751 us; speedup vs baseline: 12.3667x; 2.6226x over previous
//
#include <hip/hip_runtime.h>
#include <hip/hip_fp16.h>

#define TLEN 16384
#define HD 128

#define FOR8(X) X(0) X(1) X(2) X(3) X(4) X(5) X(6) X(7)

// ---------------------------------------------------------------------------
// Sequential GRU scan: 4 independent chains (channel-major: the reference's
// stack().transpose(0,2,1) makes "batch"=channel, "feature"=orig batch row).
// One block per chain, 768 threads = 12 waves.
//
// Stacked matrix G = [Whh (rows 0..383); Wih (rows 384..767)].
// Thread (rg = tid>>3, cb = tid&7) owns rows rg*8..+7 of G restricted to the
// 16 columns {cb*4 + 32*m + q : m,q in 0..3}  =>  128 f32 weights in NAMED
// float4 registers.  Per step each thread does 4 conflict-free broadcast
// ds_read_b128 of h (each read covers all 32 banks exactly once) and 128
// FMAs; 8-lane butterfly reduces the col-blocks; lanes cb in {0,4} write the
// 8 row results.  On ux steps waves 6..11 (gi rows) instead evaluate the
// folded 4-wide embed path gi = Wc·x + bcp (row = tid).
//
// R6 KEY FIX: amdgpu_waves_per_eu(3,3) pins occupancy to 3 waves/EU (the
// block's 12 waves on 4 SIMDs) => register budget 170.  R2-R5 showed the
// backend targets 6 waves/EU (VGPR_Count=84) when only a MINIMUM is given,
// rematerializing the weights from L2 every step (~8100 cyc/step).
// ---------------------------------------------------------------------------
__global__
__attribute__((amdgpu_flat_work_group_size(768, 768), amdgpu_waves_per_eu(3, 3)))
void gru_kernel(
    const float* __restrict__ px,
    const float* __restrict__ py,
    const float* __restrict__ vx,
    const float* __restrict__ vy,
    const float* __restrict__ Wemb,   // [128,4]
    const float* __restrict__ bemb,   // [128]
    const float* __restrict__ Wih,    // [384,128]
    const float* __restrict__ Whh,    // [384,128]
    const float* __restrict__ bih,    // [384]
    const float* __restrict__ bhh,    // [384]
    const int*   __restrict__ step_mask, // [16384]
    const int*   __restrict__ ctxp,      // [1]
    __half*      __restrict__ hs)        // [4*16384*128] f16 staging
{
    const int bb  = blockIdx.x;   // chain == channel
    const float* xsrc = (bb == 0) ? px : (bb == 1) ? py : (bb == 2) ? vx : vy;
    const int tid = threadIdx.x;
    const int rg  = tid >> 3;     // row-group 0..95 (8 stacked rows each)
    const int cb  = tid & 7;      // col-block
    const int cb4 = cb << 2;

    __shared__ float hbuf[HD];
    __shared__ float gg[768];          // stacked preactivations (no bias)
    __shared__ float hring[8][HD];     // 8-step h history for batched store
    __shared__ float xbuf[256 * 4];    // prefetched x features
    __shared__ int   uxbuf[256];       // prefetched use_x flags
    __shared__ float WembL[HD * 4];
    __shared__ float bembL[HD];
    __shared__ float biasL[768];       // [0..383]=bih, [384..767]=bhh

    // ---- weights: 32 named float4s (128 f32) ----
#define DECLW(r) float4 W##r##_0, W##r##_1, W##r##_2, W##r##_3; float a##r;
    FOR8(DECLW)
#undef DECLW
    {
        const float* Gbase = (rg < 48) ? (Whh + (rg << 3) * 128)
                                       : (Wih + ((rg - 48) << 3) * 128);
#define LOADW(r) { const float* rp = Gbase + (r) * 128 + cb4; \
        W##r##_0 = *(const float4*)(rp);      W##r##_1 = *(const float4*)(rp + 32); \
        W##r##_2 = *(const float4*)(rp + 64); W##r##_3 = *(const float4*)(rp + 96); }
        FOR8(LOADW)
#undef LOADW
    }
    if (tid < 512)                WembL[tid]        = Wemb[tid];
    if (tid >= 512 && tid < 640)  bembL[tid - 512]  = bemb[tid - 512];
    if (tid < 384) { biasL[tid] = bih[tid]; biasL[384 + tid] = bhh[tid]; }
    if (tid < HD)                 hbuf[tid]         = 0.f;
    __syncthreads();

    // ---- embed fold for the x-path (threads 384..767 <-> gi rows 0..383):
    // Wc[row][f] = sum_j Wih[row][j]*Wemb[j][f];  bcp = Wc·bemb (NO bih —
    // phase B adds bih uniformly for both x- and h-paths).
    float wc0 = 0.f, wc1 = 0.f, wc2 = 0.f, wc3 = 0.f, bcp = 0.f;
    if (tid >= 384) {
        const float* wr = Wih + (size_t)(tid - 384) * 128;
        #pragma unroll 4
        for (int j = 0; j < 128; ++j) {
            const float w = wr[j];
            const float4 e = *(const float4*)&WembL[j * 4];
            wc0 = fmaf(w, e.x, wc0); wc1 = fmaf(w, e.y, wc1);
            wc2 = fmaf(w, e.z, wc2); wc3 = fmaf(w, e.w, wc3);
            bcp = fmaf(w, bembL[j], bcp);
        }
    }
    const int ctxm = (ctxp[0] < 1) ? 1 : ctxp[0];

    for (int t0 = 0; t0 < TLEN; t0 += 256) {
        // prefetch x + use_x (prev step's trailing barrier protects xbuf)
        if (tid < 256) {
            const int gt = t0 + tid;
            xbuf[tid*4+0] = xsrc[0*TLEN + gt];
            xbuf[tid*4+1] = xsrc[1*TLEN + gt];
            xbuf[tid*4+2] = xsrc[2*TLEN + gt];
            xbuf[tid*4+3] = xsrc[3*TLEN + gt];
            uxbuf[tid] = ((gt < ctxm) || (step_mask[gt] == 0)) ? 1 : 0;
        }
        __syncthreads();
        for (int tt = 0; tt < 256; ++tt) {
            const int ux = __builtin_amdgcn_readfirstlane(uxbuf[tt]);
            if (!ux || tid < 384) {     // wave-uniform
                const float4 hA = *(const float4*)&hbuf[cb4];
                const float4 hB = *(const float4*)&hbuf[cb4 + 32];
                const float4 hC = *(const float4*)&hbuf[cb4 + 64];
                const float4 hD = *(const float4*)&hbuf[cb4 + 96];
#define ZA(r) a##r = 0.f;
                FOR8(ZA)
#undef ZA
#define RF(r) \
  a##r = fmaf(W##r##_0.x, hA.x, a##r); a##r = fmaf(W##r##_0.y, hA.y, a##r); \
  a##r = fmaf(W##r##_0.z, hA.z, a##r); a##r = fmaf(W##r##_0.w, hA.w, a##r); \
  a##r = fmaf(W##r##_1.x, hB.x, a##r); a##r = fmaf(W##r##_1.y, hB.y, a##r); \
  a##r = fmaf(W##r##_1.z, hB.z, a##r); a##r = fmaf(W##r##_1.w, hB.w, a##r); \
  a##r = fmaf(W##r##_2.x, hC.x, a##r); a##r = fmaf(W##r##_2.y, hC.y, a##r); \
  a##r = fmaf(W##r##_2.z, hC.z, a##r); a##r = fmaf(W##r##_2.w, hC.w, a##r); \
  a##r = fmaf(W##r##_3.x, hD.x, a##r); a##r = fmaf(W##r##_3.y, hD.y, a##r); \
  a##r = fmaf(W##r##_3.z, hD.z, a##r); a##r = fmaf(W##r##_3.w, hD.w, a##r);
                FOR8(RF)
#undef RF
#define RD(r) a##r += __shfl_xor(a##r, 1, 64); \
              a##r += __shfl_xor(a##r, 2, 64); \
              a##r += __shfl_xor(a##r, 4, 64);
                FOR8(RD)
#undef RD
                if ((cb & 3) == 0) {
                    const float4 v = (cb == 0) ? make_float4(a0, a1, a2, a3)
                                               : make_float4(a4, a5, a6, a7);
                    *(float4*)&gg[(rg << 3) + cb] = v;
                }
            }
            if (ux && tid >= 384) {     // x-path: row = tid (gi rows 384..767)
                const float4 xv = *(const float4*)&xbuf[tt * 4];
                float g = bcp;
                g = fmaf(wc0, xv.x, g); g = fmaf(wc1, xv.y, g);
                g = fmaf(wc2, xv.z, g); g = fmaf(wc3, xv.w, g);
                gg[tid] = g;
            }
            __syncthreads();
            // gates + state update (PyTorch GRUCell: r,z,n order)
            if (tid < HD) {
                const float gir = gg[384 + tid] + biasL[tid];
                const float ghr = gg[      tid] + biasL[384 + tid];
                const float giz = gg[512 + tid] + biasL[128 + tid];
                const float ghz = gg[128 + tid] + biasL[512 + tid];
                const float gin = gg[640 + tid] + biasL[256 + tid];
                const float ghn = gg[256 + tid] + biasL[640 + tid];
                const float r    = 1.f / (1.f + __expf(-(gir + ghr)));
                const float z    = 1.f / (1.f + __expf(-(giz + ghz)));
                const float npre = fmaf(r, ghn, gin);
                const float e2   = __expf(2.f * npre);
                const float n    = 1.f - 2.f / (e2 + 1.f);       // tanh
                const float hold = hbuf[tid];
                const float hnew = fmaf(z, hold - n, n);         // (1-z)n + z h
                hbuf[tid] = hnew;
                hring[tt & 7][tid] = hnew;
            }
            __syncthreads();
            // batched hs flush every 8 steps (overlaps next compute phase)
            if ((tt & 7) == 7 && tid >= 128 && tid < 256) {
                const int q = tid - 128;
                const int base = bb * TLEN + t0 + tt - 7;
                #pragma unroll
                for (int j = 0; j < 8; ++j) {
                    hs[(size_t)(base + j) * HD + q] = __float2half(hring[j][q]);
                }
            }
        }
    }
}

// ---------------------------------------------------------------------------
// Head MLP over all 65536 hidden states: thread-per-row, weights uniform in
// LDS (broadcast reads), h in registers, y1 in padded LDS (stride 65).
// ---------------------------------------------------------------------------
__global__ __launch_bounds__(64) void head_kernel(
    const float*  __restrict__ W1,  // [64,128]
    const float*  __restrict__ b1,  // [64]
    const float*  __restrict__ W2,  // [64,64]
    const float*  __restrict__ b2,  // [64]
    const float*  __restrict__ W3,  // [2,64]
    const float*  __restrict__ b3,  // [2]
    const __half* __restrict__ hs,
    float*        __restrict__ out)
{
    __shared__ float W1L[64 * 128];
    __shared__ float W2L[64 * 64];
    __shared__ float W3L[2 * 64];
    __shared__ float b1L[64], b2L[64], b3L[2];
    __shared__ float y1L[64 * 65];   // per-thread row, stride 65 (bank pad)

    const int tid = threadIdx.x;
    {
        float4* dst1 = (float4*)W1L; const float4* src1 = (const float4*)W1;
        for (int i = tid; i < 2048; i += 64) dst1[i] = src1[i];
        float4* dst2 = (float4*)W2L; const float4* src2 = (const float4*)W2;
        for (int i = tid; i < 1024; i += 64) dst2[i] = src2[i];
        if (tid < 32) ((float4*)W3L)[tid] = ((const float4*)W3)[tid];
        b1L[tid] = b1[tid];
        b2L[tid] = b2[tid];
        if (tid < 2) b3L[tid] = b3[tid];
    }
    __syncthreads();

    const int row = blockIdx.x * 64 + tid;   // row = bb*16384 + t
    float h[128];
    {
        const uint4* hp = (const uint4*)(hs + (size_t)row * HD);
        #pragma unroll
        for (int c = 0; c < 16; ++c) {
            uint4 q = hp[c];
            const __half2* hh = (const __half2*)&q;
            #pragma unroll
            for (int d = 0; d < 4; ++d) {
                const float2 f = __half22float2(hh[d]);
                h[c*8 + d*2 + 0] = f.x;
                h[c*8 + d*2 + 1] = f.y;
            }
        }
    }
    // layer 1: y1 = elu(W1 h + b1)
    for (int l = 0; l < 64; ++l) {
        float a0 = b1L[l], a1 = 0.f;
        #pragma unroll
        for (int j = 0; j < 128; j += 4) {
            const float4 w = *(const float4*)&W1L[l*128 + j];
            a0 = fmaf(w.x, h[j+0], a0);
            a1 = fmaf(w.y, h[j+1], a1);
            a0 = fmaf(w.z, h[j+2], a0);
            a1 = fmaf(w.w, h[j+3], a1);
        }
        const float acc = a0 + a1;
        y1L[tid * 65 + l] = (acc > 0.f) ? acc : (__expf(acc) - 1.f);
    }
    // layer 2 + layer 3 fused: y3 += W3 * elu(W2 y1 + b2)
    float y30 = b3L[0], y31 = b3L[1];
    for (int l = 0; l < 64; ++l) {
        float a0 = b2L[l], a1 = 0.f;
        const int yb = tid * 65;
        #pragma unroll
        for (int j = 0; j < 64; j += 4) {
            const float4 w = *(const float4*)&W2L[l*64 + j];
            a0 = fmaf(w.x, y1L[yb + j+0], a0);
            a1 = fmaf(w.y, y1L[yb + j+1], a1);
            a0 = fmaf(w.z, y1L[yb + j+2], a0);
            a1 = fmaf(w.w, y1L[yb + j+3], a1);
        }
        const float acc = a0 + a1;
        const float v = (acc > 0.f) ? acc : (__expf(acc) - 1.f);
        y30 = fmaf(W3L[l],      v, y30);
        y31 = fmaf(W3L[64 + l], v, y31);
    }
    out[row]            = y30;
    out[4 * TLEN + row] = y31;
}

extern "C" void kernel_launch(void* const* d_in, const int* in_sizes, int n_in,
                              void* d_out, int out_size, void* d_ws, size_t ws_size,
                              hipStream_t stream) {
    const float* px   = (const float*)d_in[0];
    const float* py   = (const float*)d_in[1];
    const float* vx   = (const float*)d_in[2];
    const float* vy   = (const float*)d_in[3];
    const float* Wemb = (const float*)d_in[4];
    const float* bemb = (const float*)d_in[5];
    const float* Wih  = (const float*)d_in[6];
    const float* Whh  = (const float*)d_in[7];
    const float* bih  = (const float*)d_in[8];
    const float* bhh  = (const float*)d_in[9];
    const float* W1   = (const float*)d_in[10];
    const float* b1   = (const float*)d_in[11];
    const float* W2   = (const float*)d_in[12];
    const float* b2   = (const float*)d_in[13];
    const float* W3   = (const float*)d_in[14];
    const float* b3   = (const float*)d_in[15];
    const int* step_mask = (const int*)d_in[16];
    const int* ctx       = (const int*)d_in[17];
    __half* hs = (__half*)d_ws;          // 4*16384*128 f16 = 16.8 MB
    float* out = (float*)d_out;          // f32, [2][4][16384] flat

    hipLaunchKernelGGL(gru_kernel, dim3(4), dim3(768), 0, stream,
                       px, py, vx, vy, Wemb, bemb, Wih, Whh, bih, bhh,
                       step_mask, ctx, hs);
    hipLaunchKernelGGL(head_kernel, dim3(1024), dim3(64), 0, stream,
                       W1, b1, W2, b2, W3, b3, hs, out);
}

// Round 7
// 18775.418 us; speedup vs baseline: 13.9385x; 1.1271x over previous
//
#include <hip/hip_runtime.h>
#include <hip/hip_fp16.h>

#define TLEN 16384
#define HD 128

typedef _Float16 half2t __attribute__((ext_vector_type(2)));

__device__ __forceinline__ half2t u2h(unsigned int u) {
    union { unsigned int u; half2t h; } c; c.u = u; return c.h;
}
__device__ __forceinline__ unsigned short f2h_bits(float f) {
    union { _Float16 h; unsigned short s; } c; c.h = (_Float16)f; return c.s;
}

#define FORR(X) X(0) X(1) X(2) X(3) X(4) X(5)

// ---------------------------------------------------------------------------
// Sequential GRU scan: 4 independent chains (channel-major — the reference's
// stack().transpose(0,2,1) makes "batch"=channel, "feature"=orig batch row).
// One block per chain, 1024 threads = 16 waves (4 waves/EU, pinned).
//
// Stacked G = [Whh (rows 0..383); Wih (rows 384..767)].
// Thread (rg=tid>>3, cb=tid&7) owns rows 6rg..6rg+5 × cols 16cb..16cb+15,
// stored as 48 NAMED f16-pair registers; per step: 2 conflict-free
// ds_read_b128 of packed-f16 h, 48 v_dot2_f32_f16 (f32 accum), 3-level
// 8-lane butterfly, lane cb==0 writes 6 row results.  On ux steps waves
// 8..13 instead evaluate the folded embed path gi = Wc·x + bcp.
//
// R7 KEY CHANGE vs R2-R6 (VGPR_Count pinned at 84 by the backend, which
// REMATERIALIZES loop-invariant weight loads instead of keeping them live —
// L1-BW bound ~3100 cyc/step): shrink weights to 48 packed VGPRs so they
// are register-resident under any occupancy target, and halve FMA issue
// via dot2.  h recurrence state stays f32 in a phase-B register; only the
// matvec inputs are f16.
// ---------------------------------------------------------------------------
__global__
__attribute__((amdgpu_flat_work_group_size(1024, 1024), amdgpu_waves_per_eu(4, 4)))
void gru_kernel(
    const float* __restrict__ px,
    const float* __restrict__ py,
    const float* __restrict__ vx,
    const float* __restrict__ vy,
    const float* __restrict__ Wemb,   // [128,4]
    const float* __restrict__ bemb,   // [128]
    const float* __restrict__ Wih,    // [384,128]
    const float* __restrict__ Whh,    // [384,128]
    const float* __restrict__ bih,    // [384]
    const float* __restrict__ bhh,    // [384]
    const int*   __restrict__ step_mask, // [16384]
    const int*   __restrict__ ctxp,      // [1]
    unsigned short* __restrict__ hs)     // [4*16384*128] f16-bits staging
{
    const int bb  = blockIdx.x;   // chain == channel
    const float* xsrc = (bb == 0) ? px : (bb == 1) ? py : (bb == 2) ? vx : vy;
    const int tid = threadIdx.x;
    const int rg  = tid >> 3;     // row-group 0..127 (6 stacked rows each)
    const int cb  = tid & 7;      // col-block (16 cols = 8 f16 pairs)

    __shared__ alignas(16) _Float16 hpack[HD];   // h as packed f16
    __shared__ float gg[768];          // stacked preactivations (no bias)
    __shared__ unsigned short hring[8][HD];      // 8-step f16 history
    __shared__ float xbuf[256 * 4];    // prefetched x features
    __shared__ int   uxbuf[256];       // prefetched use_x flags
    __shared__ float WembL[HD * 4];
    __shared__ float bembL[HD];
    __shared__ float biasL[768];       // [0..383]=bih, [384..767]=bhh

    // ---- weights: 48 named f16-pair registers ----
#define DECLR(r) half2t w##r##_0, w##r##_1, w##r##_2, w##r##_3, \
                        w##r##_4, w##r##_5, w##r##_6, w##r##_7; float aa##r;
    FORR(DECLR)
#undef DECLR
    {
        const float* Gbase = (rg < 64) ? (Whh + (size_t)(6 * rg) * 128)
                                       : (Wih + (size_t)(6 * rg - 384) * 128);
#define LOADR(r) { const float* rp = Gbase + (r) * 128 + (cb << 4); \
        const float4 f0 = *(const float4*)(rp);     const float4 f1 = *(const float4*)(rp + 4); \
        const float4 f2 = *(const float4*)(rp + 8); const float4 f3 = *(const float4*)(rp + 12); \
        w##r##_0.x = (_Float16)f0.x; w##r##_0.y = (_Float16)f0.y; \
        w##r##_1.x = (_Float16)f0.z; w##r##_1.y = (_Float16)f0.w; \
        w##r##_2.x = (_Float16)f1.x; w##r##_2.y = (_Float16)f1.y; \
        w##r##_3.x = (_Float16)f1.z; w##r##_3.y = (_Float16)f1.w; \
        w##r##_4.x = (_Float16)f2.x; w##r##_4.y = (_Float16)f2.y; \
        w##r##_5.x = (_Float16)f2.z; w##r##_5.y = (_Float16)f2.w; \
        w##r##_6.x = (_Float16)f3.x; w##r##_6.y = (_Float16)f3.y; \
        w##r##_7.x = (_Float16)f3.z; w##r##_7.y = (_Float16)f3.w; }
        FORR(LOADR)
#undef LOADR
    }
    if (tid < 512)                WembL[tid]        = Wemb[tid];
    if (tid >= 512 && tid < 640)  bembL[tid - 512]  = bemb[tid - 512];
    if (tid < 384) { biasL[tid] = bih[tid]; biasL[384 + tid] = bhh[tid]; }
    if (tid < HD)                 hpack[tid]        = (_Float16)0.f;
    __syncthreads();

    // ---- embed fold for the x-path (threads 512..895 <-> gi rows 0..383):
    // Wc[row][f] = sum_j Wih[row][j]*Wemb[j][f];  bcp = Wc·bemb (bih added
    // uniformly in phase B).
    float wc0 = 0.f, wc1 = 0.f, wc2 = 0.f, wc3 = 0.f, bcp = 0.f;
    if (tid >= 512 && tid < 896) {
        const float* wr = Wih + (size_t)(tid - 512) * 128;
        #pragma unroll 4
        for (int j = 0; j < 128; ++j) {
            const float w = wr[j];
            const float4 e = *(const float4*)&WembL[j * 4];
            wc0 = fmaf(w, e.x, wc0); wc1 = fmaf(w, e.y, wc1);
            wc2 = fmaf(w, e.z, wc2); wc3 = fmaf(w, e.w, wc3);
            bcp = fmaf(w, bembL[j], bcp);
        }
    }
    const int ctxm = (ctxp[0] < 1) ? 1 : ctxp[0];
    float hold = 0.f;   // phase-B f32 recurrence state (thread tid<128 owns h[tid])

    const unsigned int* hpk = (const unsigned int*)hpack;

    for (int t0 = 0; t0 < TLEN; t0 += 256) {
        if (tid < 256) {
            const int gt = t0 + tid;
            xbuf[tid*4+0] = xsrc[0*TLEN + gt];
            xbuf[tid*4+1] = xsrc[1*TLEN + gt];
            xbuf[tid*4+2] = xsrc[2*TLEN + gt];
            xbuf[tid*4+3] = xsrc[3*TLEN + gt];
            uxbuf[tid] = ((gt < ctxm) || (step_mask[gt] == 0)) ? 1 : 0;
        }
        __syncthreads();
        for (int tt = 0; tt < 256; ++tt) {
            const int ux = __builtin_amdgcn_readfirstlane(uxbuf[tt]);
            if (!ux || tid < 512) {     // wave-uniform
                const uint4 hA = *(const uint4*)(hpk + (cb << 3));
                const uint4 hB = *(const uint4*)(hpk + (cb << 3) + 4);
                const half2t hp0 = u2h(hA.x), hp1 = u2h(hA.y),
                             hp2 = u2h(hA.z), hp3 = u2h(hA.w),
                             hp4 = u2h(hB.x), hp5 = u2h(hB.y),
                             hp6 = u2h(hB.z), hp7 = u2h(hB.w);
#define MV(r) { float a = 0.f; \
        a = __builtin_amdgcn_fdot2(w##r##_0, hp0, a, false); \
        a = __builtin_amdgcn_fdot2(w##r##_1, hp1, a, false); \
        a = __builtin_amdgcn_fdot2(w##r##_2, hp2, a, false); \
        a = __builtin_amdgcn_fdot2(w##r##_3, hp3, a, false); \
        a = __builtin_amdgcn_fdot2(w##r##_4, hp4, a, false); \
        a = __builtin_amdgcn_fdot2(w##r##_5, hp5, a, false); \
        a = __builtin_amdgcn_fdot2(w##r##_6, hp6, a, false); \
        a = __builtin_amdgcn_fdot2(w##r##_7, hp7, a, false); \
        aa##r = a; }
                FORR(MV)
#undef MV
#define RD(r) aa##r += __shfl_xor(aa##r, 1, 64); \
              aa##r += __shfl_xor(aa##r, 2, 64); \
              aa##r += __shfl_xor(aa##r, 4, 64);
                FORR(RD)
#undef RD
                if (cb == 0) {
                    float* gp = &gg[6 * rg];
                    *(float2*)(gp + 0) = make_float2(aa0, aa1);
                    *(float2*)(gp + 2) = make_float2(aa2, aa3);
                    *(float2*)(gp + 4) = make_float2(aa4, aa5);
                }
            }
            if (ux && tid >= 512 && tid < 896) {  // x-path: gi row tid-512
                const float4 xv = *(const float4*)&xbuf[tt * 4];
                float g = bcp;
                g = fmaf(wc0, xv.x, g); g = fmaf(wc1, xv.y, g);
                g = fmaf(wc2, xv.z, g); g = fmaf(wc3, xv.w, g);
                gg[tid - 128] = g;    // gg[384 + (tid-512)]
            }
            __syncthreads();
            // gates + state update (PyTorch GRUCell: r,z,n order)
            if (tid < HD) {
                const float gir = gg[384 + tid] + biasL[tid];
                const float ghr = gg[      tid] + biasL[384 + tid];
                const float giz = gg[512 + tid] + biasL[128 + tid];
                const float ghz = gg[128 + tid] + biasL[512 + tid];
                const float gin = gg[640 + tid] + biasL[256 + tid];
                const float ghn = gg[256 + tid] + biasL[640 + tid];
                const float r    = 1.f / (1.f + __expf(-(gir + ghr)));
                const float z    = 1.f / (1.f + __expf(-(giz + ghz)));
                const float npre = fmaf(r, ghn, gin);
                const float e2   = __expf(2.f * npre);
                const float n    = 1.f - 2.f / (e2 + 1.f);       // tanh
                const float hnew = fmaf(z, hold - n, n);         // (1-z)n + z h
                hold = hnew;
                hpack[tid] = (_Float16)hnew;
                hring[tt & 7][tid] = f2h_bits(hnew);
            }
            __syncthreads();
            // batched hs flush every 8 steps (overlaps next compute phase)
            if ((tt & 7) == 7 && tid >= 128 && tid < 256) {
                const int q = tid - 128;
                const int base = bb * TLEN + t0 + tt - 7;
                #pragma unroll
                for (int j = 0; j < 8; ++j) {
                    hs[(size_t)(base + j) * HD + q] = hring[j][q];
                }
            }
        }
    }
}

// ---------------------------------------------------------------------------
// Head MLP over all 65536 hidden states: thread-per-row, weights uniform in
// LDS (broadcast reads), h in registers, y1 in padded LDS (stride 65).
// ---------------------------------------------------------------------------
__global__ __launch_bounds__(64) void head_kernel(
    const float*  __restrict__ W1,  // [64,128]
    const float*  __restrict__ b1,  // [64]
    const float*  __restrict__ W2,  // [64,64]
    const float*  __restrict__ b2,  // [64]
    const float*  __restrict__ W3,  // [2,64]
    const float*  __restrict__ b3,  // [2]
    const __half* __restrict__ hs,
    float*        __restrict__ out)
{
    __shared__ float W1L[64 * 128];
    __shared__ float W2L[64 * 64];
    __shared__ float W3L[2 * 64];
    __shared__ float b1L[64], b2L[64], b3L[2];
    __shared__ float y1L[64 * 65];   // per-thread row, stride 65 (bank pad)

    const int tid = threadIdx.x;
    {
        float4* dst1 = (float4*)W1L; const float4* src1 = (const float4*)W1;
        for (int i = tid; i < 2048; i += 64) dst1[i] = src1[i];
        float4* dst2 = (float4*)W2L; const float4* src2 = (const float4*)W2;
        for (int i = tid; i < 1024; i += 64) dst2[i] = src2[i];
        if (tid < 32) ((float4*)W3L)[tid] = ((const float4*)W3)[tid];
        b1L[tid] = b1[tid];
        b2L[tid] = b2[tid];
        if (tid < 2) b3L[tid] = b3[tid];
    }
    __syncthreads();

    const int row = blockIdx.x * 64 + tid;   // row = bb*16384 + t
    float h[128];
    {
        const uint4* hp = (const uint4*)(hs + (size_t)row * HD);
        #pragma unroll
        for (int c = 0; c < 16; ++c) {
            uint4 q = hp[c];
            const __half2* hh = (const __half2*)&q;
            #pragma unroll
            for (int d = 0; d < 4; ++d) {
                const float2 f = __half22float2(hh[d]);
                h[c*8 + d*2 + 0] = f.x;
                h[c*8 + d*2 + 1] = f.y;
            }
        }
    }
    // layer 1: y1 = elu(W1 h + b1)
    for (int l = 0; l < 64; ++l) {
        float a0 = b1L[l], a1 = 0.f;
        #pragma unroll
        for (int j = 0; j < 128; j += 4) {
            const float4 w = *(const float4*)&W1L[l*128 + j];
            a0 = fmaf(w.x, h[j+0], a0);
            a1 = fmaf(w.y, h[j+1], a1);
            a0 = fmaf(w.z, h[j+2], a0);
            a1 = fmaf(w.w, h[j+3], a1);
        }
        const float acc = a0 + a1;
        y1L[tid * 65 + l] = (acc > 0.f) ? acc : (__expf(acc) - 1.f);
    }
    // layer 2 + layer 3 fused: y3 += W3 * elu(W2 y1 + b2)
    float y30 = b3L[0], y31 = b3L[1];
    for (int l = 0; l < 64; ++l) {
        float a0 = b2L[l], a1 = 0.f;
        const int yb = tid * 65;
        #pragma unroll
        for (int j = 0; j < 64; j += 4) {
            const float4 w = *(const float4*)&W2L[l*64 + j];
            a0 = fmaf(w.x, y1L[yb + j+0], a0);
            a1 = fmaf(w.y, y1L[yb + j+1], a1);
            a0 = fmaf(w.z, y1L[yb + j+2], a0);
            a1 = fmaf(w.w, y1L[yb + j+3], a1);
        }
        const float acc = a0 + a1;
        const float v = (acc > 0.f) ? acc : (__expf(acc) - 1.f);
        y30 = fmaf(W3L[l],      v, y30);
        y31 = fmaf(W3L[64 + l], v, y31);
    }
    out[row]            = y30;
    out[4 * TLEN + row] = y31;
}

extern "C" void kernel_launch(void* const* d_in, const int* in_sizes, int n_in,
                              void* d_out, int out_size, void* d_ws, size_t ws_size,
                              hipStream_t stream) {
    const float* px   = (const float*)d_in[0];
    const float* py   = (const float*)d_in[1];
    const float* vx   = (const float*)d_in[2];
    const float* vy   = (const float*)d_in[3];
    const float* Wemb = (const float*)d_in[4];
    const float* bemb = (const float*)d_in[5];
    const float* Wih  = (const float*)d_in[6];
    const float* Whh  = (const float*)d_in[7];
    const float* bih  = (const float*)d_in[8];
    const float* bhh  = (const float*)d_in[9];
    const float* W1   = (const float*)d_in[10];
    const float* b1   = (const float*)d_in[11];
    const float* W2   = (const float*)d_in[12];
    const float* b2   = (const float*)d_in[13];
    const float* W3   = (const float*)d_in[14];
    const float* b3   = (const float*)d_in[15];
    const int* step_mask = (const int*)d_in[16];
    const int* ctx       = (const int*)d_in[17];
    unsigned short* hs = (unsigned short*)d_ws;  // 4*16384*128 f16-bits = 16.8 MB
    float* out = (float*)d_out;                  // f32, [2][4][16384] flat

    hipLaunchKernelGGL(gru_kernel, dim3(4), dim3(1024), 0, stream,
                       px, py, vx, vy, Wemb, bemb, Wih, Whh, bih, bhh,
                       step_mask, ctx, hs);
    hipLaunchKernelGGL(head_kernel, dim3(1024), dim3(64), 0, stream,
                       W1, b1, W2, b2, W3, b3, (const __half*)hs, out);
}

// Round 8
// 11426.437 us; speedup vs baseline: 22.9032x; 1.6432x over previous
//
#include <hip/hip_runtime.h>
#include <hip/hip_fp16.h>

#define TLEN 16384
#define HD 128

typedef _Float16 half2t __attribute__((ext_vector_type(2)));

__device__ __forceinline__ half2t u2h(unsigned int u) {
    union { unsigned int u; half2t h; } c; c.u = u; return c.h;
}
__device__ __forceinline__ unsigned short f2h_bits(float f) {
    union { _Float16 h; unsigned short s; } c; c.h = (_Float16)f; return c.s;
}
__device__ __forceinline__ half2t mkh2(float a, float b) {
    half2t h; h.x = (_Float16)a; h.y = (_Float16)b; return h;
}
// quad_perm DPP cross-lane (VALU pipe, NOT ds_swizzle): xor1 = [1,0,3,2]=0xB1,
// xor2 = [2,3,0,1]=0x4E.  cb = lane&3 so quad groups align with col-blocks.
#define DPP_XOR1(x) __int_as_float(__builtin_amdgcn_update_dpp(0, __float_as_int(x), 0xB1, 0xF, 0xF, true))
#define DPP_XOR2(x) __int_as_float(__builtin_amdgcn_update_dpp(0, __float_as_int(x), 0x4E, 0xF, 0xF, true))

#define FOR3(X) X(0) X(1) X(2)

// ---------------------------------------------------------------------------
// Sequential GRU scan: 4 independent chains (channel-major — the reference's
// stack().transpose(0,2,1) makes "batch"=channel, "feature"=orig batch row).
// One block per chain, 1024 threads = 16 waves (4/EU pinned).
//
// Stacked G = [Whh (rows 0..383); Wih (rows 384..767)].
// Thread (rg=tid>>2, cb=tid&3) owns rows 3rg..3rg+2 × cols 32cb..32cb+31
// as 48 packed-f16 NAMED registers.  Per step: 4 multicast ds_read_b128 of
// f16 h, 48 v_dot2_f32_f16, then a 5-op ALL-DPP merge tree (R7 lesson:
// __shfl_xor = ds_swizzle = LDS pipe; 18/thread made R7 LDS-bound at
// ~2750 cyc/step).  Lane cb<3 holds the full sum of row 3rg+cb and writes
// it (+bias, preloaded in a register) with one ds_write_b32.
// gg2 = float2{gh,gi} per gate-row; phase B = 3 ds_read_b64, no bias reads.
// On ux steps waves 8..13 run the folded embed path instead (bih in bcp).
// ---------------------------------------------------------------------------
__global__
__attribute__((amdgpu_flat_work_group_size(1024, 1024), amdgpu_waves_per_eu(4, 4)))
void gru_kernel(
    const float* __restrict__ px,
    const float* __restrict__ py,
    const float* __restrict__ vx,
    const float* __restrict__ vy,
    const float* __restrict__ Wemb,   // [128,4]
    const float* __restrict__ bemb,   // [128]
    const float* __restrict__ Wih,    // [384,128]
    const float* __restrict__ Whh,    // [384,128]
    const float* __restrict__ bih,    // [384]
    const float* __restrict__ bhh,    // [384]
    const int*   __restrict__ step_mask, // [16384]
    const int*   __restrict__ ctxp,      // [1]
    unsigned short* __restrict__ hs)     // [4*16384*128] f16-bits staging
{
    const int bb  = blockIdx.x;   // chain == channel
    const float* xsrc = (bb == 0) ? px : (bb == 1) ? py : (bb == 2) ? vx : vy;
    const int tid = threadIdx.x;
    const int rg  = tid >> 2;     // row-group 0..255 (3 stacked rows each)
    const int cb  = tid & 3;      // col-block (32 cols)
    const int b0  = cb & 1, b1 = cb >> 1;

    __shared__ alignas(16) _Float16 hpack[HD];   // h as packed f16
    __shared__ float2 gg2[384];        // {gh+bhh, gi+bih} per gate-row
    __shared__ unsigned short hring[8][HD];      // 8-step f16 history
    __shared__ float xbuf[256 * 4];    // prefetched x features
    __shared__ int   uxbuf[256];       // prefetched use_x flags
    __shared__ float WembL[HD * 4];
    __shared__ float bembL[HD];

    // ---- weights: 48 named packed-f16 registers (3 rows x 16 half2) ----
#define DECLR(r) half2t w##r##_0, w##r##_1, w##r##_2,  w##r##_3,  w##r##_4,  \
                        w##r##_5, w##r##_6, w##r##_7,  w##r##_8,  w##r##_9,  \
                        w##r##_10, w##r##_11, w##r##_12, w##r##_13, \
                        w##r##_14, w##r##_15;
    FOR3(DECLR)
#undef DECLR
    {
        const float* Gbase = (rg < 128) ? (Whh + (size_t)(3 * rg) * 128)
                                        : (Wih + (size_t)(3 * rg - 384) * 128);
#define LOADR(r) { const float* rp = Gbase + (r) * 128 + (cb << 5); \
        const float4 f0 = *(const float4*)(rp+ 0), f1 = *(const float4*)(rp+ 4); \
        const float4 f2 = *(const float4*)(rp+ 8), f3 = *(const float4*)(rp+12); \
        const float4 f4 = *(const float4*)(rp+16), f5 = *(const float4*)(rp+20); \
        const float4 f6 = *(const float4*)(rp+24), f7 = *(const float4*)(rp+28); \
        w##r##_0  = mkh2(f0.x,f0.y); w##r##_1  = mkh2(f0.z,f0.w); \
        w##r##_2  = mkh2(f1.x,f1.y); w##r##_3  = mkh2(f1.z,f1.w); \
        w##r##_4  = mkh2(f2.x,f2.y); w##r##_5  = mkh2(f2.z,f2.w); \
        w##r##_6  = mkh2(f3.x,f3.y); w##r##_7  = mkh2(f3.z,f3.w); \
        w##r##_8  = mkh2(f4.x,f4.y); w##r##_9  = mkh2(f4.z,f4.w); \
        w##r##_10 = mkh2(f5.x,f5.y); w##r##_11 = mkh2(f5.z,f5.w); \
        w##r##_12 = mkh2(f6.x,f6.y); w##r##_13 = mkh2(f6.z,f6.w); \
        w##r##_14 = mkh2(f7.x,f7.y); w##r##_15 = mkh2(f7.z,f7.w); }
        FOR3(LOADR)
#undef LOADR
    }
    // writer identity: lane cb in {0,1,2} writes G-row 3rg+cb
    const int  gr    = 3 * rg + ((cb < 3) ? cb : 2);
    const float wbias = (gr < 384) ? bhh[gr] : bih[gr - 384];
    const int  waddr = (gr < 384) ? (2 * gr) : (2 * (gr - 384) + 1);
    float* ggf = (float*)gg2;

    if (tid < 512)                WembL[tid]        = Wemb[tid];
    if (tid >= 512 && tid < 640)  bembL[tid - 512]  = bemb[tid - 512];
    if (tid < HD)                 hpack[tid]        = (_Float16)0.f;
    __syncthreads();

    // ---- embed fold for x-path (threads 512..895 <-> gi rows 0..383):
    // bcp includes bih (phase B adds no bias).
    float wc0 = 0.f, wc1 = 0.f, wc2 = 0.f, wc3 = 0.f, bcp = 0.f;
    if (tid >= 512 && tid < 896) {
        const float* wr = Wih + (size_t)(tid - 512) * 128;
        #pragma unroll 4
        for (int j = 0; j < 128; ++j) {
            const float w = wr[j];
            const float4 e = *(const float4*)&WembL[j * 4];
            wc0 = fmaf(w, e.x, wc0); wc1 = fmaf(w, e.y, wc1);
            wc2 = fmaf(w, e.z, wc2); wc3 = fmaf(w, e.w, wc3);
            bcp = fmaf(w, bembL[j], bcp);
        }
        bcp += bih[tid - 512];
    }
    const int ctxm = (ctxp[0] < 1) ? 1 : ctxp[0];
    float hold = 0.f;   // phase-B f32 recurrence state (tid<128 owns h[tid])

    const uint4* hq = (const uint4*)hpack;

    for (int t0 = 0; t0 < TLEN; t0 += 256) {
        if (tid < 256) {
            const int gt = t0 + tid;
            xbuf[tid*4+0] = xsrc[0*TLEN + gt];
            xbuf[tid*4+1] = xsrc[1*TLEN + gt];
            xbuf[tid*4+2] = xsrc[2*TLEN + gt];
            xbuf[tid*4+3] = xsrc[3*TLEN + gt];
            uxbuf[tid] = ((gt < ctxm) || (step_mask[gt] == 0)) ? 1 : 0;
        }
        __syncthreads();
        for (int tt = 0; tt < 256; ++tt) {
            const int ux = __builtin_amdgcn_readfirstlane(uxbuf[tt]);
            if (!ux || tid < 512) {     // wave-uniform (waves 0-7 always)
                // h slice: cols 32cb..+31 = 4 multicast ds_read_b128
                const uint4 q0 = hq[(cb << 2) + 0];
                const uint4 q1 = hq[(cb << 2) + 1];
                const uint4 q2 = hq[(cb << 2) + 2];
                const uint4 q3 = hq[(cb << 2) + 3];
                const half2t hp0  = u2h(q0.x), hp1  = u2h(q0.y),
                             hp2  = u2h(q0.z), hp3  = u2h(q0.w),
                             hp4  = u2h(q1.x), hp5  = u2h(q1.y),
                             hp6  = u2h(q1.z), hp7  = u2h(q1.w),
                             hp8  = u2h(q2.x), hp9  = u2h(q2.y),
                             hp10 = u2h(q2.z), hp11 = u2h(q2.w),
                             hp12 = u2h(q3.x), hp13 = u2h(q3.y),
                             hp14 = u2h(q3.z), hp15 = u2h(q3.w);
                float a0, a1, a2;
#define MV(r, acc) { float a = 0.f; \
        a = __builtin_amdgcn_fdot2(w##r##_0,  hp0,  a, false); \
        a = __builtin_amdgcn_fdot2(w##r##_1,  hp1,  a, false); \
        a = __builtin_amdgcn_fdot2(w##r##_2,  hp2,  a, false); \
        a = __builtin_amdgcn_fdot2(w##r##_3,  hp3,  a, false); \
        a = __builtin_amdgcn_fdot2(w##r##_4,  hp4,  a, false); \
        a = __builtin_amdgcn_fdot2(w##r##_5,  hp5,  a, false); \
        a = __builtin_amdgcn_fdot2(w##r##_6,  hp6,  a, false); \
        a = __builtin_amdgcn_fdot2(w##r##_7,  hp7,  a, false); \
        a = __builtin_amdgcn_fdot2(w##r##_8,  hp8,  a, false); \
        a = __builtin_amdgcn_fdot2(w##r##_9,  hp9,  a, false); \
        a = __builtin_amdgcn_fdot2(w##r##_10, hp10, a, false); \
        a = __builtin_amdgcn_fdot2(w##r##_11, hp11, a, false); \
        a = __builtin_amdgcn_fdot2(w##r##_12, hp12, a, false); \
        a = __builtin_amdgcn_fdot2(w##r##_13, hp13, a, false); \
        a = __builtin_amdgcn_fdot2(w##r##_14, hp14, a, false); \
        a = __builtin_amdgcn_fdot2(w##r##_15, hp15, a, false); \
        acc = a; }
                MV(0, a0) MV(1, a1) MV(2, a2)
#undef MV
                // all-DPP merge tree: 3 values over 4 lanes, rows by lane bits
                const float s0 = b0 ? a0 : a1;       // send
                const float m0 = b0 ? a1 : a0;       // keep
                const float c0 = m0 + DPP_XOR1(s0);  // row 3rg+(b0) over pairs
                const float c1 = a2 + DPP_XOR1(a2);  // row 3rg+2 over pairs
                const float s1 = b1 ? c0 : c1;
                const float m1 = b1 ? c1 : c0;
                const float e  = m1 + DPP_XOR2(s1);  // full sum, row by cb
                if (cb < 3) ggf[waddr] = e + wbias;
            }
            if (ux && tid >= 512 && tid < 896) {  // x-path: gi row tid-512
                const float4 xv = *(const float4*)&xbuf[tt * 4];
                float g = bcp;
                g = fmaf(wc0, xv.x, g); g = fmaf(wc1, xv.y, g);
                g = fmaf(wc2, xv.z, g); g = fmaf(wc3, xv.w, g);
                ggf[2 * (tid - 512) + 1] = g;
            }
            __syncthreads();
            // gates + state update (PyTorch GRUCell: r,z,n order)
            if (tid < HD) {
                const float2 g_r = gg2[tid];         // {ghr+bhh, gir+bih}
                const float2 g_z = gg2[128 + tid];
                const float2 g_n = gg2[256 + tid];
                const float r    = 1.f / (1.f + __expf(-(g_r.x + g_r.y)));
                const float z    = 1.f / (1.f + __expf(-(g_z.x + g_z.y)));
                const float npre = fmaf(r, g_n.x, g_n.y);   // gin + r*ghn
                const float e2   = __expf(2.f * npre);
                const float n    = 1.f - 2.f / (e2 + 1.f);  // tanh
                const float hnew = fmaf(z, hold - n, n);    // (1-z)n + z h
                hold = hnew;
                hpack[tid] = (_Float16)hnew;
                hring[tt & 7][tid] = f2h_bits(hnew);
            }
            __syncthreads();
            // batched hs flush every 8 steps (overlaps next compute phase)
            if ((tt & 7) == 7 && tid >= 128 && tid < 256) {
                const int q = tid - 128;
                const int base = bb * TLEN + t0 + tt - 7;
                #pragma unroll
                for (int j = 0; j < 8; ++j) {
                    hs[(size_t)(base + j) * HD + q] = hring[j][q];
                }
            }
        }
    }
}

// ---------------------------------------------------------------------------
// Head MLP over all 65536 hidden states: thread-per-row, weights uniform in
// LDS (broadcast reads), h in registers, y1 in padded LDS (stride 65).
// ---------------------------------------------------------------------------
__global__ __launch_bounds__(64) void head_kernel(
    const float*  __restrict__ W1,  // [64,128]
    const float*  __restrict__ b1,  // [64]
    const float*  __restrict__ W2,  // [64,64]
    const float*  __restrict__ b2,  // [64]
    const float*  __restrict__ W3,  // [2,64]
    const float*  __restrict__ b3,  // [2]
    const __half* __restrict__ hs,
    float*        __restrict__ out)
{
    __shared__ float W1L[64 * 128];
    __shared__ float W2L[64 * 64];
    __shared__ float W3L[2 * 64];
    __shared__ float b1L[64], b2L[64], b3L[2];
    __shared__ float y1L[64 * 65];   // per-thread row, stride 65 (bank pad)

    const int tid = threadIdx.x;
    {
        float4* dst1 = (float4*)W1L; const float4* src1 = (const float4*)W1;
        for (int i = tid; i < 2048; i += 64) dst1[i] = src1[i];
        float4* dst2 = (float4*)W2L; const float4* src2 = (const float4*)W2;
        for (int i = tid; i < 1024; i += 64) dst2[i] = src2[i];
        if (tid < 32) ((float4*)W3L)[tid] = ((const float4*)W3)[tid];
        b1L[tid] = b1[tid];
        b2L[tid] = b2[tid];
        if (tid < 2) b3L[tid] = b3[tid];
    }
    __syncthreads();

    const int row = blockIdx.x * 64 + tid;   // row = bb*16384 + t
    float h[128];
    {
        const uint4* hp = (const uint4*)(hs + (size_t)row * HD);
        #pragma unroll
        for (int c = 0; c < 16; ++c) {
            uint4 q = hp[c];
            const __half2* hh = (const __half2*)&q;
            #pragma unroll
            for (int d = 0; d < 4; ++d) {
                const float2 f = __half22float2(hh[d]);
                h[c*8 + d*2 + 0] = f.x;
                h[c*8 + d*2 + 1] = f.y;
            }
        }
    }
    // layer 1: y1 = elu(W1 h + b1)
    for (int l = 0; l < 64; ++l) {
        float a0 = b1L[l], a1 = 0.f;
        #pragma unroll
        for (int j = 0; j < 128; j += 4) {
            const float4 w = *(const float4*)&W1L[l*128 + j];
            a0 = fmaf(w.x, h[j+0], a0);
            a1 = fmaf(w.y, h[j+1], a1);
            a0 = fmaf(w.z, h[j+2], a0);
            a1 = fmaf(w.w, h[j+3], a1);
        }
        const float acc = a0 + a1;
        y1L[tid * 65 + l] = (acc > 0.f) ? acc : (__expf(acc) - 1.f);
    }
    // layer 2 + layer 3 fused: y3 += W3 * elu(W2 y1 + b2)
    float y30 = b3L[0], y31 = b3L[1];
    for (int l = 0; l < 64; ++l) {
        float a0 = b2L[l], a1 = 0.f;
        const int yb = tid * 65;
        #pragma unroll
        for (int j = 0; j < 64; j += 4) {
            const float4 w = *(const float4*)&W2L[l*64 + j];
            a0 = fmaf(w.x, y1L[yb + j+0], a0);
            a1 = fmaf(w.y, y1L[yb + j+1], a1);
            a0 = fmaf(w.z, y1L[yb + j+2], a0);
            a1 = fmaf(w.w, y1L[yb + j+3], a1);
        }
        const float acc = a0 + a1;
        const float v = (acc > 0.f) ? acc : (__expf(acc) - 1.f);
        y30 = fmaf(W3L[l],      v, y30);
        y31 = fmaf(W3L[64 + l], v, y31);
    }
    out[row]            = y30;
    out[4 * TLEN + row] = y31;
}

extern "C" void kernel_launch(void* const* d_in, const int* in_sizes, int n_in,
                              void* d_out, int out_size, void* d_ws, size_t ws_size,
                              hipStream_t stream) {
    const float* px   = (const float*)d_in[0];
    const float* py   = (const float*)d_in[1];
    const float* vx   = (const float*)d_in[2];
    const float* vy   = (const float*)d_in[3];
    const float* Wemb = (const float*)d_in[4];
    const float* bemb = (const float*)d_in[5];
    const float* Wih  = (const float*)d_in[6];
    const float* Whh  = (const float*)d_in[7];
    const float* bih  = (const float*)d_in[8];
    const float* bhh  = (const float*)d_in[9];
    const float* W1   = (const float*)d_in[10];
    const float* b1   = (const float*)d_in[11];
    const float* W2   = (const float*)d_in[12];
    const float* b2   = (const float*)d_in[13];
    const float* W3   = (const float*)d_in[14];
    const float* b3   = (const float*)d_in[15];
    const int* step_mask = (const int*)d_in[16];
    const int* ctx       = (const int*)d_in[17];
    unsigned short* hs = (unsigned short*)d_ws;  // 4*16384*128 f16-bits = 16.8 MB
    float* out = (float*)d_out;                  // f32, [2][4][16384] flat

    hipLaunchKernelGGL(gru_kernel, dim3(4), dim3(1024), 0, stream,
                       px, py, vx, vy, Wemb, bemb, Wih, Whh, bih, bhh,
                       step_mask, ctx, hs);
    hipLaunchKernelGGL(head_kernel, dim3(1024), dim3(64), 0, stream,
                       W1, b1, W2, b2, W3, b3, (const __half*)hs, out);
}